// Round 2
// baseline (383.042 us; speedup 1.0000x reference)
//
#include <hip/hip_runtime.h>

// Problem constants (match reference setup_inputs)
constexpr int Bb = 64;
constexpr int T  = 4096;
constexpr int D  = 256;
constexpr int A  = 10;
// output layout (floats): anchors [T*A*2] | proposals [B*T*A*2] | cls [B*T*A*2] | bbox [B*T*A*2]
constexpr size_t ANCHORS_N  = (size_t)T * A * 2;         // 81920
constexpr size_t PER_TENSOR = (size_t)Bb * T * A * 2;    // 5242880
constexpr int ROWS = 64;   // rows per block

__global__ void anchors_k(float* __restrict__ out) {
    int i = blockIdx.x * 256 + threadIdx.x;   // over T*A
    if (i >= T * A) return;
    int t = i / A;
    int a = i - t * A;
    float L = fmaf((float)a, 160.0f / 9.0f, 40.0f);  // linspace(40,200,10)
    float h = 0.5f * (L - 1.0f);
    reinterpret_cast<float2*>(out)[i] = make_float2((float)t - h, (float)t + h);
}

// LDS swizzle: row-major [64][256] floats, 16B-granule XOR of row into the
// column bits. Keeps total at exactly 64 KB (no pad) and makes both the
// staging writes and the lane=row ds_read_b128 stream hit the 8-access/bank
// floor (1024B / 128B-per-clk), i.e. conflict-free.
__device__ __forceinline__ int swz(int r, int d) {
    return r * D + (d ^ ((r & 7) << 2));
}

__global__ __launch_bounds__(256, 2) void rpn_k(
    const float* __restrict__ x,
    const float* __restrict__ Wc, const float* __restrict__ bc,
    const float* __restrict__ Wb, const float* __restrict__ bb,
    float* __restrict__ out_prop, float* __restrict__ out_cls,
    float* __restrict__ out_bbox)
{
    __shared__ float xs[ROWS * D];   // 65536 B

    const int tid = threadIdx.x;
    const int base_row = blockIdx.x * ROWS;

    // ---- stage 64 rows (64 KB), fully coalesced: each wave-iter = one row ----
    const float* __restrict__ src = x + (size_t)base_row * D;
#pragma unroll
    for (int it = 0; it < 16; ++it) {
        const int f = it * 1024 + tid * 4;     // flat float index in tile
        const int r = f >> 8;
        const int d = f & (D - 1);
        const float4 v = *reinterpret_cast<const float4*>(src + f);
        *reinterpret_cast<float4*>(&xs[swz(r, d)]) = v;
    }
    __syncthreads();

    const int wave = tid >> 6;
    const int lane = tid & 63;
    const int row  = base_row + lane;

    // wave 0: cls[0..9], wave 1: cls[10..19], wave 2: bbox[0..9], wave 3: bbox[10..19]
    // readfirstlane => compiler-provable wave-uniform => s_load weight stream
    const int sel = __builtin_amdgcn_readfirstlane(wave >> 1);
    const int og0 = __builtin_amdgcn_readfirstlane((wave & 1) * 10);

    const float* __restrict__ Wbase = (const float*)((const char*)Wc +
        (size_t)sel * (size_t)((const char*)Wb - (const char*)Wc));
    const float* __restrict__ Bbase = (const float*)((const char*)bc +
        (size_t)sel * (size_t)((const char*)bb - (const char*)bc));

    float acc[10];
#pragma unroll
    for (int j = 0; j < 10; ++j) acc[j] = Bbase[og0 + j];

    const int   sw   = (lane & 7) << 2;
    const float* __restrict__ xrow = &xs[lane * D];

#pragma unroll 4
    for (int d0 = 0; d0 < D; d0 += 4) {
        const float4 xv = *reinterpret_cast<const float4*>(xrow + (d0 ^ sw));
#pragma unroll
        for (int j = 0; j < 10; ++j) {
            const float4 wv = *reinterpret_cast<const float4*>(Wbase + (og0 + j) * D + d0);
            acc[j] = fmaf(xv.w, wv.w, fmaf(xv.z, wv.z,
                     fmaf(xv.y, wv.y, fmaf(xv.x, wv.x, acc[j]))));
        }
    }

    const size_t obase = (size_t)row * 20 + og0;   // 8B aligned

    if (wave < 2) {
        float* __restrict__ dst = out_cls + obase;
#pragma unroll
        for (int j = 0; j < 5; ++j)
            reinterpret_cast<float2*>(dst)[j] = make_float2(acc[2*j], acc[2*j+1]);
    } else {
        float* __restrict__ dst = out_bbox + obase;
#pragma unroll
        for (int j = 0; j < 5; ++j)
            reinterpret_cast<float2*>(dst)[j] = make_float2(acc[2*j], acc[2*j+1]);

        // proposals for anchors a0..a0+4 (dx,dl pairs live in this wave)
        const int t  = row & (T - 1);
        const int a0 = (wave & 1) * 5;
        float* __restrict__ dstp = out_prop + obase;   // row*20 + a0*2
#pragma unroll
        for (int a = 0; a < 5; ++a) {
            const float L   = fmaf((float)(a0 + a), 160.0f / 9.0f, 40.0f);
            const float dx  = acc[2*a];
            const float dl  = acc[2*a + 1];
            const float ctr = fmaf(dx, L, (float)t);
            const float pl  = __expf(dl) * L;
            const float h   = 0.5f * (pl - 1.0f);
            const float s = fminf(fmaxf(ctr - h, 0.0f), (float)(T - 1));
            const float e = fminf(fmaxf(ctr + h, 0.0f), (float)(T - 1));
            reinterpret_cast<float2*>(dstp)[a] = make_float2(s, e);
        }
    }
}

extern "C" void kernel_launch(void* const* d_in, const int* in_sizes, int n_in,
                              void* d_out, int out_size, void* d_ws, size_t ws_size,
                              hipStream_t stream) {
    const float* x  = (const float*)d_in[0];
    const float* Wc = (const float*)d_in[1];
    const float* bc = (const float*)d_in[2];
    const float* Wb = (const float*)d_in[3];
    const float* bb = (const float*)d_in[4];

    float* out     = (float*)d_out;
    float* anchors = out;
    float* prop    = out + ANCHORS_N;
    float* cls     = out + ANCHORS_N + PER_TENSOR;
    float* bbox    = out + ANCHORS_N + 2 * PER_TENSOR;

    anchors_k<<<(T * A + 255) / 256, 256, 0, stream>>>(anchors);

    const int rows = Bb * T;                  // 262144
    rpn_k<<<rows / ROWS, 256, 0, stream>>>(x, Wc, bc, Wb, bb, prop, cls, bbox);
}

// Round 3
// 197.961 us; speedup vs baseline: 1.9349x; 1.9349x over previous
//
#include <hip/hip_runtime.h>

// Problem constants (match reference setup_inputs)
constexpr int Bb = 64;
constexpr int T  = 4096;
constexpr int D  = 256;
constexpr int A  = 10;
// output layout (floats): anchors [T*A*2] | proposals [B*T*A*2] | cls [B*T*A*2] | bbox [B*T*A*2]
constexpr size_t ANCHORS_N  = (size_t)T * A * 2;         // 81920
constexpr size_t PER_TENSOR = (size_t)Bb * T * A * 2;    // 5242880
constexpr int ROWS  = 64;    // rows per block tile
constexpr int BLOCK = 512;   // 8 waves

__global__ void anchors_k(float* __restrict__ out) {
    int i = blockIdx.x * 256 + threadIdx.x;   // over T*A
    if (i >= T * A) return;
    int t = i / A;
    int a = i - t * A;
    float L = fmaf((float)a, 160.0f / 9.0f, 40.0f);  // linspace(40,200,10)
    float h = 0.5f * (L - 1.0f);
    reinterpret_cast<float2*>(out)[i] = make_float2((float)t - h, (float)t + h);
}

// x tile swizzle: 16B-granule XOR of (row&15) into the column bits.
// Compute-phase lane=row ds_read_b128 then spreads the 64 lanes across all
// 16 bank-groups (the 8-clk 1KB/instr floor, no extra serialization), and
// staging writes (full-row contiguous per 16-lane group) stay conflict-free.
__device__ __forceinline__ int swz(int r, int d) {
    return r * D + (d ^ ((r & 15) << 2));
}

__global__ __launch_bounds__(BLOCK, 2) void rpn_k(
    const float* __restrict__ x,
    const float* __restrict__ Wc, const float* __restrict__ bc,
    const float* __restrict__ Wb, const float* __restrict__ bb,
    float* __restrict__ out_prop, float* __restrict__ out_cls,
    float* __restrict__ out_bbox)
{
    __shared__ float xs[ROWS * D];   // 65536 B; reused as output staging
    float* ls = xs;                  // [64][41]: cls 0..19, bbox 20..39, pad

    const int tid = threadIdx.x;
    const int base_row = blockIdx.x * ROWS;

    // ---- stage 64 rows (64 KB), fully coalesced ----
    const float* __restrict__ src = x + (size_t)base_row * D;
#pragma unroll
    for (int it = 0; it < 8; ++it) {
        const int f = it * 2048 + tid * 4;     // flat float index in tile
        const int r = f >> 8;
        const int d = f & (D - 1);
        const float4 v = *reinterpret_cast<const float4*>(src + f);
        *reinterpret_cast<float4*>(&xs[swz(r, d)]) = v;
    }
    __syncthreads();

    const int wave = tid >> 6;
    const int lane = tid & 63;

    // wave 0..3: cls outputs [5w,5w+5) ; wave 4..7: bbox outputs [5(w-4),..)
    const int sel = __builtin_amdgcn_readfirstlane(wave >> 2);
    const int og0 = __builtin_amdgcn_readfirstlane((wave & 3) * 5);

    const float* __restrict__ Wbase = (const float*)((const char*)Wc +
        (size_t)sel * (size_t)((const char*)Wb - (const char*)Wc));
    const float* __restrict__ Bbase = (const float*)((const char*)bc +
        (size_t)sel * (size_t)((const char*)bb - (const char*)bc));

    float acc[5];
#pragma unroll
    for (int j = 0; j < 5; ++j) acc[j] = Bbase[og0 + j];

    const int sw = (lane & 15) << 2;
    const float* __restrict__ xrow = &xs[lane * D];

#pragma unroll 8
    for (int d0 = 0; d0 < D; d0 += 4) {
        const float4 xv = *reinterpret_cast<const float4*>(xrow + (d0 ^ sw));
#pragma unroll
        for (int j = 0; j < 5; ++j) {
            const float4 wv = *reinterpret_cast<const float4*>(Wbase + (og0 + j) * D + d0);
            acc[j] = fmaf(xv.w, wv.w, fmaf(xv.z, wv.z,
                     fmaf(xv.y, wv.y, fmaf(xv.x, wv.x, acc[j]))));
        }
    }

    __syncthreads();   // xs no longer needed as input tile

    // ---- stash accs: ls[row][sel*20 + og0 + j], stride 41 (odd => ~2-way banks)
#pragma unroll
    for (int j = 0; j < 5; ++j)
        ls[lane * 41 + sel * 20 + og0 + j] = acc[j];
    __syncthreads();

    // ---- coalesced epilogue: dense float2 streams per tensor ----
    const size_t obase = (size_t)base_row * 20;   // tile's flat float offset

    // cls: 1280 floats = 640 float2
    for (int i = tid; i < 640; i += BLOCK) {
        const int r = i / 10, c = (i % 10) * 2;
        reinterpret_cast<float2*>(out_cls + obase)[i] =
            make_float2(ls[r * 41 + c], ls[r * 41 + c + 1]);
    }
    // bbox
    for (int i = tid; i < 640; i += BLOCK) {
        const int r = i / 10, c = (i % 10) * 2;
        reinterpret_cast<float2*>(out_bbox + obase)[i] =
            make_float2(ls[r * 41 + 20 + c], ls[r * 41 + 20 + c + 1]);
    }
    // proposals: decode from LDS-resident bbox values
    for (int i = tid; i < 640; i += BLOCK) {
        const int r = i / 10, a = i % 10;
        const float dx = ls[r * 41 + 20 + 2 * a];
        const float dl = ls[r * 41 + 20 + 2 * a + 1];
        const int   t  = (base_row + r) & (T - 1);
        const float L  = fmaf((float)a, 160.0f / 9.0f, 40.0f);
        const float ctr = fmaf(dx, L, (float)t);
        const float pl  = __expf(dl) * L;
        const float h   = 0.5f * (pl - 1.0f);
        const float s = fminf(fmaxf(ctr - h, 0.0f), (float)(T - 1));
        const float e = fminf(fmaxf(ctr + h, 0.0f), (float)(T - 1));
        reinterpret_cast<float2*>(out_prop + obase)[i] = make_float2(s, e);
    }
}

extern "C" void kernel_launch(void* const* d_in, const int* in_sizes, int n_in,
                              void* d_out, int out_size, void* d_ws, size_t ws_size,
                              hipStream_t stream) {
    const float* x  = (const float*)d_in[0];
    const float* Wc = (const float*)d_in[1];
    const float* bc = (const float*)d_in[2];
    const float* Wb = (const float*)d_in[3];
    const float* bb = (const float*)d_in[4];

    float* out     = (float*)d_out;
    float* anchors = out;
    float* prop    = out + ANCHORS_N;
    float* cls     = out + ANCHORS_N + PER_TENSOR;
    float* bbox    = out + ANCHORS_N + 2 * PER_TENSOR;

    anchors_k<<<(T * A + 255) / 256, 256, 0, stream>>>(anchors);

    const int rows = Bb * T;                  // 262144
    rpn_k<<<rows / ROWS, BLOCK, 0, stream>>>(x, Wc, bc, Wb, bb, prop, cls, bbox);
}

// Round 4
// 95.525 us; speedup vs baseline: 4.0099x; 2.0724x over previous
//
#include <hip/hip_runtime.h>

// Problem constants (match reference setup_inputs)
constexpr int Bb = 64;
constexpr int T  = 4096;
constexpr int D  = 256;   // K
constexpr int A  = 10;
constexpr size_t ANCHORS_N  = (size_t)T * A * 2;         // 81920
constexpr size_t PER_TENSOR = (size_t)Bb * T * A * 2;    // 5242880
constexpr int M  = Bb * T;        // 262144 rows
constexpr int MT = M / 16;        // 16384 M-tiles of 16 rows

typedef __attribute__((ext_vector_type(8))) short short8v;  // 8 bf16 (4 VGPR)
typedef __attribute__((ext_vector_type(4))) float f32x4;    // MFMA acc

__device__ __forceinline__ unsigned short f2b(float f) {    // fp32 -> bf16 RNE
    unsigned u = __builtin_bit_cast(unsigned, f);
    return (unsigned short)((u + 0x7FFFu + ((u >> 16) & 1u)) >> 16);
}
__device__ __forceinline__ float b2f(unsigned short h) {
    return __builtin_bit_cast(float, (unsigned)h << 16);
}

__global__ void anchors_k(float* __restrict__ out) {
    int i = blockIdx.x * 256 + threadIdx.x;   // over T*A
    if (i >= T * A) return;
    int t = i / A;
    int a = i - t * A;
    float L = fmaf((float)a, 160.0f / 9.0f, 40.0f);  // linspace(40,200,10)
    float h = 0.5f * (L - 1.0f);
    reinterpret_cast<float2*>(out)[i] = make_float2((float)t - h, (float)t + h);
}

// GEMM: [M x 256] * [256 x 48]  (48 = 20 cls | 20 bbox | 8 pad), MFMA 16x16x32 bf16.
// A-frag: lane holds A[row = lane&15][k = (lane>>4)*8 + e], e=0..7
// B-frag: lane holds B[k = (lane>>4)*8 + e][col = lane&15]
// C-frag: lane reg r -> C[row = (lane>>4)*4 + r][col = lane&15]   (m89-verified)
__global__ __launch_bounds__(256, 2) void rpn_mfma(
    const float* __restrict__ x,
    const float* __restrict__ Wc, const float* __restrict__ bc,
    const float* __restrict__ Wb, const float* __restrict__ bb,
    float* __restrict__ out_prop, float* __restrict__ out_cls,
    float* __restrict__ out_bbox)
{
    const int lane = threadIdx.x & 63;
    const int wid    = blockIdx.x * (blockDim.x >> 6) + (threadIdx.x >> 6);
    const int nwaves = gridDim.x * (blockDim.x >> 6);
    const int c  = lane & 15;   // frag col (A-row / B-col / C-col)
    const int kc = lane >> 4;   // k-chunk 0..3

    // per-lane weight row + bias for the 3 N-tiles (col -> output j = nt*16+c)
    const float* wrow[3];
    float bias[3];
    bool  pad[3];
    wrow[0] = Wc + c * D;            bias[0] = bc[c];      pad[0] = false;
    if (c < 4) { wrow[1] = Wc + (16 + c) * D; bias[1] = bc[16 + c]; }
    else       { wrow[1] = Wb + (c - 4) * D;  bias[1] = bb[c - 4];  }
    pad[1] = false;
    if (c < 8) { wrow[2] = Wb + (12 + c) * D; bias[2] = bb[12 + c]; pad[2] = false; }
    else       { wrow[2] = Wb;                bias[2] = 0.0f;       pad[2] = true;  }

    // build B fragments once per wave: wf[ntile][kstep], bf16 RNE (96 VGPR)
    short8v wf[3][8];
#pragma unroll
    for (int nt = 0; nt < 3; ++nt) {
#pragma unroll
        for (int ks = 0; ks < 8; ++ks) {
            const float* p = wrow[nt] + kc * 8 + ks * 32;
            const float4 a = *reinterpret_cast<const float4*>(p);
            const float4 b = *reinterpret_cast<const float4*>(p + 4);
            short8v h;
            h[0] = (short)f2b(a.x); h[1] = (short)f2b(a.y);
            h[2] = (short)f2b(a.z); h[3] = (short)f2b(a.w);
            h[4] = (short)f2b(b.x); h[5] = (short)f2b(b.y);
            h[6] = (short)f2b(b.z); h[7] = (short)f2b(b.w);
            if (pad[nt]) {
#pragma unroll
                for (int e = 0; e < 8; ++e) h[e] = 0;
            }
            wf[nt][ks] = h;
        }
    }

    for (int mt = wid; mt < MT; mt += nwaves) {
        // A base: row = mt*16 + c, k-chunk kc
        const float* xr = x + (size_t)(mt * 16 + c) * D + kc * 8;

        f32x4 ah0 = {0,0,0,0}, ah1 = {0,0,0,0}, ah2 = {0,0,0,0};
        f32x4 al0 = {0,0,0,0}, al1 = {0,0,0,0}, al2 = {0,0,0,0};

#pragma unroll
        for (int ks = 0; ks < 8; ++ks) {
            const float4 a = *reinterpret_cast<const float4*>(xr + ks * 32);
            const float4 b = *reinterpret_cast<const float4*>(xr + ks * 32 + 4);
            float v[8] = {a.x, a.y, a.z, a.w, b.x, b.y, b.z, b.w};
            short8v xh, xl;
#pragma unroll
            for (int e = 0; e < 8; ++e) {
                unsigned short hb = f2b(v[e]);
                xh[e] = (short)hb;
                xl[e] = (short)f2b(v[e] - b2f(hb));   // residual, ~2^-9 of v
            }
            ah0 = __builtin_amdgcn_mfma_f32_16x16x32_bf16(xh, wf[0][ks], ah0, 0, 0, 0);
            al0 = __builtin_amdgcn_mfma_f32_16x16x32_bf16(xl, wf[0][ks], al0, 0, 0, 0);
            ah1 = __builtin_amdgcn_mfma_f32_16x16x32_bf16(xh, wf[1][ks], ah1, 0, 0, 0);
            al1 = __builtin_amdgcn_mfma_f32_16x16x32_bf16(xl, wf[1][ks], al1, 0, 0, 0);
            ah2 = __builtin_amdgcn_mfma_f32_16x16x32_bf16(xh, wf[2][ks], ah2, 0, 0, 0);
            al2 = __builtin_amdgcn_mfma_f32_16x16x32_bf16(xl, wf[2][ks], al2, 0, 0, 0);
        }

        // epilogue: C[row = kc*4 + r][col = c]
#pragma unroll
        for (int r = 0; r < 4; ++r) {
            const int    R  = mt * 16 + kc * 4 + r;
            const size_t rb = (size_t)R * 20;

            const float v0 = ah0[r] + al0[r] + bias[0];
            out_cls[rb + c] = v0;                                // cls j = c (0..15)

            const float v1  = ah1[r] + al1[r] + bias[1];
            const float v1p = __shfl_xor(v1, 1);
            const float v2  = ah2[r] + al2[r] + bias[2];
            const float v2p = __shfl_xor(v2, 1);

            const int t = R & (T - 1);

            if (c < 4) {
                out_cls[rb + 16 + c] = v1;                       // cls j = 16..19
            } else {
                const int jb = c - 4;                            // bbox 0..11
                out_bbox[rb + jb] = v1;
                if (!(jb & 1)) {
                    const int   an = jb >> 1;
                    const float L  = fmaf((float)an, 160.0f / 9.0f, 40.0f);
                    const float ctr = fmaf(v1, L, (float)t);
                    const float pl  = __expf(v1p) * L;
                    const float hh  = 0.5f * (pl - 1.0f);
                    const float s = fminf(fmaxf(ctr - hh, 0.0f), (float)(T - 1));
                    const float e = fminf(fmaxf(ctr + hh, 0.0f), (float)(T - 1));
                    *reinterpret_cast<float2*>(out_prop + rb + jb) = make_float2(s, e);
                }
            }
            if (c < 8) {
                const int jb = 12 + c;                           // bbox 12..19
                out_bbox[rb + jb] = v2;
                if (!(jb & 1)) {
                    const int   an = jb >> 1;
                    const float L  = fmaf((float)an, 160.0f / 9.0f, 40.0f);
                    const float ctr = fmaf(v2, L, (float)t);
                    const float pl  = __expf(v2p) * L;
                    const float hh  = 0.5f * (pl - 1.0f);
                    const float s = fminf(fmaxf(ctr - hh, 0.0f), (float)(T - 1));
                    const float e = fminf(fmaxf(ctr + hh, 0.0f), (float)(T - 1));
                    *reinterpret_cast<float2*>(out_prop + rb + jb) = make_float2(s, e);
                }
            }
        }
    }
}

extern "C" void kernel_launch(void* const* d_in, const int* in_sizes, int n_in,
                              void* d_out, int out_size, void* d_ws, size_t ws_size,
                              hipStream_t stream) {
    const float* x  = (const float*)d_in[0];
    const float* Wc = (const float*)d_in[1];
    const float* bc = (const float*)d_in[2];
    const float* Wb = (const float*)d_in[3];
    const float* bb = (const float*)d_in[4];

    float* out     = (float*)d_out;
    float* anchors = out;
    float* prop    = out + ANCHORS_N;
    float* cls     = out + ANCHORS_N + PER_TENSOR;
    float* bbox    = out + ANCHORS_N + 2 * PER_TENSOR;

    anchors_k<<<(T * A + 255) / 256, 256, 0, stream>>>(anchors);

    // 1024 blocks x 4 waves = 4096 waves -> 4 M-tiles each
    rpn_mfma<<<1024, 256, 0, stream>>>(x, Wc, bc, Wb, bb, prop, cls, bbox);
}

// Round 5
// 73.639 us; speedup vs baseline: 5.2016x; 1.2972x over previous
//
#include <hip/hip_runtime.h>
#include <hip/hip_bf16.h>

// Problem constants (match reference setup_inputs)
constexpr int Bb = 64;
constexpr int T  = 4096;
constexpr int D  = 256;   // K
constexpr int A  = 10;
constexpr size_t ANCHORS_N  = (size_t)T * A * 2;         // 81920
constexpr size_t PER_TENSOR = (size_t)Bb * T * A * 2;    // 5242880
constexpr int M      = Bb * T;        // 262144 rows
constexpr int MT     = M / 16;        // 16384 m-tiles of 16 rows
constexpr int NBLK   = 512;           // 128-thread blocks (2 waves)
constexpr int NWAVES = NBLK * 2;      // 1024 waves, 1/SIMD (LDS-limited: 2 blk/CU)
constexpr int TPW    = MT / NWAVES;   // 16 tiles per wave

typedef __attribute__((ext_vector_type(8))) short short8v;  // 8 bf16
typedef __attribute__((ext_vector_type(4))) float f32x4;    // MFMA acc

__device__ __forceinline__ unsigned short f2b(float f) {    // RNE via v_cvt (pk-fusable)
    return __builtin_bit_cast(unsigned short, __float2bfloat16(f));
}
__device__ __forceinline__ float b2f(unsigned short h) {
    return __builtin_bit_cast(float, (unsigned)h << 16);
}

// GEMM: [M x 256] * [256 x 48]  (48 = 20 cls | 20 bbox | 8 pad), MFMA 16x16x32 bf16.
// A-frag: lane holds A[row = lane&15][k = (lane>>4)*8 + e]  (R4-verified)
// C-frag: lane reg r -> C[row = (lane>>4)*4 + r][col = lane&15]
//
// x staged per-wave via global_load_lds (async, dbuf). LDS layout within a row:
// 16B chunk' = chunk ^ (row&7)  — applied on the global SOURCE address (linear
// LDS dest, rule #21) and on the ds_read address. Compute-phase ds_read_b128
// (16 rows x 4 kc) then hits all 8 bank-groups evenly = 8-clk floor.
__global__ __launch_bounds__(128, 1) void rpn_mfma(
    const float* __restrict__ x,
    const float* __restrict__ Wc, const float* __restrict__ bc,
    const float* __restrict__ Wb, const float* __restrict__ bb,
    float* __restrict__ out_anch, float* __restrict__ out_prop,
    float* __restrict__ out_cls,  float* __restrict__ out_bbox)
{
    __shared__ float xs[2][2][16 * 256];   // [wave][buf][16 rows x 256] = 64 KB

    const int tid  = threadIdx.x;
    const int w    = tid >> 6;
    const int lane = tid & 63;
    const int wid  = blockIdx.x * 2 + w;
    const int c    = lane & 15;   // frag col (A-row / B-col / C-col)
    const int kc   = lane >> 4;   // k-chunk 0..3
    const int r3   = c & 7;

    float* const lb0 = &xs[w][0][0];
    float* const lb1 = &xs[w][1][0];

    auto stage = [&](float* lbuf, int mt) {
        const float* gbase = x + (size_t)mt * (16 * D);
#pragma unroll
        for (int r = 0; r < 16; ++r) {
            // lane l carries global chunk (l ^ (r&7)) -> linear LDS chunk l
            const float* g = gbase + r * D + ((lane ^ (r & 7)) << 2);
            __builtin_amdgcn_global_load_lds(
                (const __attribute__((address_space(1))) unsigned int*)g,
                (__attribute__((address_space(3))) unsigned int*)(lbuf + r * 256),
                16, 0, 0);
        }
    };

    // issue first tile immediately; write anchors under its latency
    stage(lb0, wid);
    {
        const int i = wid * 64 + lane;           // 65536 threads cover T*A=40960
        if (i < T * A) {
            const int t = i / A;
            const int a = i - t * A;
            const float L = fmaf((float)a, 160.0f / 9.0f, 40.0f);
            const float h = 0.5f * (L - 1.0f);
            reinterpret_cast<float2*>(out_anch)[i] = make_float2((float)t - h, (float)t + h);
        }
    }

    // ---- per-lane weight rows + biases for the 3 N-tiles ----
    const float* wrow[3];
    float bias[3];
    bool  pad[3];
    wrow[0] = Wc + c * D;            bias[0] = bc[c];      pad[0] = false;
    if (c < 4) { wrow[1] = Wc + (16 + c) * D; bias[1] = bc[16 + c]; }
    else       { wrow[1] = Wb + (c - 4) * D;  bias[1] = bb[c - 4];  }
    pad[1] = false;
    if (c < 8) { wrow[2] = Wb + (12 + c) * D; bias[2] = bb[12 + c]; pad[2] = false; }
    else       { wrow[2] = Wb;                bias[2] = 0.0f;       pad[2] = true;  }

    // B fragments once per wave: wf[ntile][kstep] (96 VGPR)
    short8v wf[3][8];
#pragma unroll
    for (int nt = 0; nt < 3; ++nt) {
#pragma unroll
        for (int ks = 0; ks < 8; ++ks) {
            const float* p = wrow[nt] + kc * 8 + ks * 32;
            const float4 a = *reinterpret_cast<const float4*>(p);
            const float4 b = *reinterpret_cast<const float4*>(p + 4);
            short8v h;
            h[0] = (short)f2b(a.x); h[1] = (short)f2b(a.y);
            h[2] = (short)f2b(a.z); h[3] = (short)f2b(a.w);
            h[4] = (short)f2b(b.x); h[5] = (short)f2b(b.y);
            h[6] = (short)f2b(b.z); h[7] = (short)f2b(b.w);
            if (pad[nt]) {
#pragma unroll
                for (int e = 0; e < 8; ++e) h[e] = 0;
            }
            wf[nt][ks] = h;
        }
    }

    const int offA = (((2 * kc) ^ r3) << 2);      // swizzled float offsets in row
    const int offB = (((2 * kc + 1) ^ r3) << 2);

    auto compute = [&](const float* lbuf, int mt) {
        const float* lrow = lbuf + c * 256;

        f32x4 ah0 = {0,0,0,0}, ah1 = {0,0,0,0}, ah2 = {0,0,0,0};
        f32x4 al0 = {0,0,0,0}, al1 = {0,0,0,0}, al2 = {0,0,0,0};

#pragma unroll
        for (int ks = 0; ks < 8; ++ks) {
            const float4 qa = *reinterpret_cast<const float4*>(lrow + ks * 32 + offA);
            const float4 qb = *reinterpret_cast<const float4*>(lrow + ks * 32 + offB);
            float v[8] = {qa.x, qa.y, qa.z, qa.w, qb.x, qb.y, qb.z, qb.w};
            short8v xh, xl;
#pragma unroll
            for (int e = 0; e < 8; ++e) {
                const unsigned short hb = f2b(v[e]);
                xh[e] = (short)hb;
                xl[e] = (short)f2b(v[e] - b2f(hb));   // residual
            }
            ah0 = __builtin_amdgcn_mfma_f32_16x16x32_bf16(xh, wf[0][ks], ah0, 0, 0, 0);
            al0 = __builtin_amdgcn_mfma_f32_16x16x32_bf16(xl, wf[0][ks], al0, 0, 0, 0);
            ah1 = __builtin_amdgcn_mfma_f32_16x16x32_bf16(xh, wf[1][ks], ah1, 0, 0, 0);
            al1 = __builtin_amdgcn_mfma_f32_16x16x32_bf16(xl, wf[1][ks], al1, 0, 0, 0);
            ah2 = __builtin_amdgcn_mfma_f32_16x16x32_bf16(xh, wf[2][ks], ah2, 0, 0, 0);
            al2 = __builtin_amdgcn_mfma_f32_16x16x32_bf16(xl, wf[2][ks], al2, 0, 0, 0);
        }

        // epilogue (R4-verified): C[row = kc*4 + r][col = c]
#pragma unroll
        for (int r = 0; r < 4; ++r) {
            const int    R  = mt * 16 + kc * 4 + r;
            const size_t rb = (size_t)R * 20;

            const float v0 = ah0[r] + al0[r] + bias[0];
            out_cls[rb + c] = v0;                                // cls j = 0..15

            const float v1  = ah1[r] + al1[r] + bias[1];
            const float v1p = __shfl_xor(v1, 1);
            const float v2  = ah2[r] + al2[r] + bias[2];
            const float v2p = __shfl_xor(v2, 1);

            const int t = R & (T - 1);

            if (c < 4) {
                out_cls[rb + 16 + c] = v1;                       // cls j = 16..19
            } else {
                const int jb = c - 4;                            // bbox 0..11
                out_bbox[rb + jb] = v1;
                if (!(jb & 1)) {
                    const int   an = jb >> 1;
                    const float L  = fmaf((float)an, 160.0f / 9.0f, 40.0f);
                    const float ctr = fmaf(v1, L, (float)t);
                    const float pl  = __expf(v1p) * L;
                    const float hh  = 0.5f * (pl - 1.0f);
                    const float s = fminf(fmaxf(ctr - hh, 0.0f), (float)(T - 1));
                    const float e = fminf(fmaxf(ctr + hh, 0.0f), (float)(T - 1));
                    *reinterpret_cast<float2*>(out_prop + rb + jb) = make_float2(s, e);
                }
            }
            if (c < 8) {
                const int jb = 12 + c;                           // bbox 12..19
                out_bbox[rb + jb] = v2;
                if (!(jb & 1)) {
                    const int   an = jb >> 1;
                    const float L  = fmaf((float)an, 160.0f / 9.0f, 40.0f);
                    const float ctr = fmaf(v2, L, (float)t);
                    const float pl  = __expf(v2p) * L;
                    const float hh  = 0.5f * (pl - 1.0f);
                    const float s = fminf(fmaxf(ctr - hh, 0.0f), (float)(T - 1));
                    const float e = fminf(fmaxf(ctr + hh, 0.0f), (float)(T - 1));
                    *reinterpret_cast<float2*>(out_prop + rb + jb) = make_float2(s, e);
                }
            }
        }
    };

    // wait for tile 0
    asm volatile("s_waitcnt vmcnt(0)" ::: "memory");
    __builtin_amdgcn_sched_barrier(0);

#pragma unroll 1
    for (int i = 0; i < TPW; ++i) {
        float* const cur = (i & 1) ? lb1 : lb0;
        float* const nxt = (i & 1) ? lb0 : lb1;
        if (i + 1 < TPW) stage(nxt, wid + (i + 1) * NWAVES);   // async prefetch
        compute(cur, wid + i * NWAVES);
        asm volatile("s_waitcnt vmcnt(0)" ::: "memory");        // next tile landed
        __builtin_amdgcn_sched_barrier(0);
    }
}

extern "C" void kernel_launch(void* const* d_in, const int* in_sizes, int n_in,
                              void* d_out, int out_size, void* d_ws, size_t ws_size,
                              hipStream_t stream) {
    const float* x  = (const float*)d_in[0];
    const float* Wc = (const float*)d_in[1];
    const float* bc = (const float*)d_in[2];
    const float* Wb = (const float*)d_in[3];
    const float* bb = (const float*)d_in[4];

    float* out     = (float*)d_out;
    float* anchors = out;
    float* prop    = out + ANCHORS_N;
    float* cls     = out + ANCHORS_N + PER_TENSOR;
    float* bbox    = out + ANCHORS_N + 2 * PER_TENSOR;

    rpn_mfma<<<NBLK, 128, 0, stream>>>(x, Wc, bc, Wb, bb, anchors, prop, cls, bbox);
}